// Round 16
// baseline (186.713 us; speedup 1.0000x reference)
//
#include <hip/hip_runtime.h>
#include <cstdint>

#define HSZ 32
#define TSTEPS 256
#define ISZ 6
#define NB 16

typedef _Float16 h8_t __attribute__((ext_vector_type(8)));
typedef float f4_t __attribute__((ext_vector_type(4)));

#if __has_builtin(__builtin_amdgcn_exp2f)
__device__ __forceinline__ float exp2_raw(float x) { return __builtin_amdgcn_exp2f(x); }
#else
__device__ __forceinline__ float exp2_raw(float x) { return __expf(0.69314718056f * x); }
#endif
// clamped exp2: fused-rcp forms can hit (1-INF)*rcp(INF)=NaN; cap arg at 60
// (exp2(60)=1.15e18, products stay < 1.4e36, far from f32 overflow).
__device__ __forceinline__ float exp2c(float x) { return exp2_raw(fminf(x, 60.0f)); }

// One wave (64 thr) owns 16 batch elements and the WHOLE recurrence (round-15
// structure: all 8 gate n-tiles in one wave -> i,f,g,o of one (b,u) land in
// the SAME lane; c/h update pure-register, no barriers, LDS only for the h
// transpose: 8 ds_write_b16 + 1 ds_read_b128 per step).
//
// Round-16 deltas (round-15 post-mortem: 1600 cyc/step vs 640 trans floor,
// 1 wave/SIMD -> all latency exposed):
//  1. x-part MFMAs software-pipelined one step ahead, issued BETWEEN the h
//     ds_writes and the next ds_read -> hides ~160cyc LDS RAW latency.
//  2. rcp-fusion: iv*gv = (1-eg)*rcp((1+ei)(1+eg)), h = (1-ec)*rcp((1+eo)(1+ec))
//     -> 8 trans-ops per (b,u) instead of 10 (trans floor 640->512 cyc).
//  3. bias folded into MFMA K-dim (ax[6]=1, bih[][6]=bias) -> frees 32 VGPR.
// Weights pre-scaled by -log2e (g rows by -2log2e) so all nonlinearities are
// exp2-based with no per-step argument muls.
__global__ __launch_bounds__(64, 2) void lstm_wave(
    const float* __restrict__ x,
    const float* __restrict__ W_ih,
    const float* __restrict__ W_hh,
    const float* __restrict__ b_ih,
    const float* __restrict__ b_hh,
    const float* __restrict__ W1,
    const float* __restrict__ b1,
    const float* __restrict__ W2,
    const float* __restrict__ b2,
    float* __restrict__ out)
{
    __shared__ __align__(16) _Float16 hlds[NB][40];   // h state, 80B rows (16B-aligned)
    __shared__ float w1s[64 * 34];                    // stride 34: even + conflict-free
    __shared__ float b1s[64];
    __shared__ float w2s[64];

    const int lane = threadIdx.x;
    const int n16  = lane & 15;
    const int khi  = lane >> 4;

    // ---- one-time staging ----
    for (int i = lane; i < 64 * HSZ; i += 64) w1s[(i >> 5) * 34 + (i & 31)] = W1[i];
    b1s[lane] = b1[lane];
    w2s[lane] = W2[lane];
    #pragma unroll
    for (int i = 0; i < 5; ++i) ((unsigned int*)hlds)[lane + i * 64] = 0u;  // h0 = 0

    // B-fragments, pre-scaled; bias in k=6 slot. Tile q: q0,1=i q2,3=f q4,5=g q6,7=o.
    const float LOG2E = 1.44269504f;
    h8_t bhh[8], bih[8];
    #pragma unroll
    for (int q = 0; q < 8; ++q) {
        const int grow = q * 16 + n16;
        const float s = (q == 4 || q == 5) ? (-2.0f * LOG2E) : (-LOG2E);
        const float4* p = (const float4*)(W_hh + grow * HSZ + khi * 8);
        const float4 a = p[0], b = p[1];
        bhh[q][0] = (_Float16)(s * a.x); bhh[q][1] = (_Float16)(s * a.y);
        bhh[q][2] = (_Float16)(s * a.z); bhh[q][3] = (_Float16)(s * a.w);
        bhh[q][4] = (_Float16)(s * b.x); bhh[q][5] = (_Float16)(s * b.y);
        bhh[q][6] = (_Float16)(s * b.z); bhh[q][7] = (_Float16)(s * b.w);
        bih[q][0] = (_Float16)0; bih[q][1] = (_Float16)0;
        bih[q][2] = (_Float16)0; bih[q][3] = (_Float16)0;
        bih[q][4] = (_Float16)0; bih[q][5] = (_Float16)0;
        bih[q][6] = (_Float16)0; bih[q][7] = (_Float16)0;
        if (khi == 0) {
            const float2* pi = (const float2*)(W_ih + grow * ISZ);
            const float2 i0 = pi[0], i1 = pi[1], i2 = pi[2];
            bih[q][0] = (_Float16)(s * i0.x); bih[q][1] = (_Float16)(s * i0.y);
            bih[q][2] = (_Float16)(s * i1.x); bih[q][3] = (_Float16)(s * i1.y);
            bih[q][4] = (_Float16)(s * i2.x); bih[q][5] = (_Float16)(s * i2.y);
            bih[q][6] = (_Float16)(s * (b_ih[grow] + b_hh[grow]));  // bias via ax[6]=1
        }
    }

    // x stream for batch n16 (same addr across khi lanes -> broadcast).
    const float* xb = x + (size_t)(blockIdx.x * NB + n16) * (TSTEPS * ISZ);
    float2 xn0 = ((const float2*)xb)[0], xn1 = ((const float2*)xb)[1], xn2 = ((const float2*)xb)[2];

    const f4_t zf = {0.f, 0.f, 0.f, 0.f};
    h8_t ax;
    ax[0] = (_Float16)xn0.x; ax[1] = (_Float16)xn0.y;
    ax[2] = (_Float16)xn1.x; ax[3] = (_Float16)xn1.y;
    ax[4] = (_Float16)xn2.x; ax[5] = (_Float16)xn2.y;
    ax[6] = (_Float16)1;     ax[7] = (_Float16)0;      // k=6 -> bias row

    f4_t dx[8];
    #pragma unroll
    for (int q = 0; q < 8; ++q)
        dx[q] = __builtin_amdgcn_mfma_f32_16x16x32_f16(ax, bih[q], zf, 0, 0, 0);

    {   // prefetch x(1)
        const float2* pn = (const float2*)(xb + ISZ);
        xn0 = pn[0]; xn1 = pn[1]; xn2 = pn[2];
    }

    float c[2][4] = {{0.f, 0.f, 0.f, 0.f}, {0.f, 0.f, 0.f, 0.f}};

    __builtin_amdgcn_wave_barrier();

    for (int t = 0; t < TSTEPS; ++t) {
        // h-part MFMAs: accumulate onto pipelined x-part results.
        const h8_t ah = *(const h8_t*)&hlds[n16][khi * 8];
        f4_t d[8];
        #pragma unroll
        for (int q = 0; q < 8; ++q)
            d[q] = __builtin_amdgcn_mfma_f32_16x16x32_f16(ah, bhh[q], dx[q], 0, 0, 0);

        // lane-local activations + c/h update (batch khi*4+r, unit hh*16+n16)
        #pragma unroll
        for (int hh = 0; hh < 2; ++hh) {
            #pragma unroll
            for (int r = 0; r < 4; ++r) {
                const float ei = exp2c(d[0 + hh][r]);
                const float ef = exp2c(d[2 + hh][r]);
                const float eg = exp2c(d[4 + hh][r]);
                const float eo = exp2c(d[6 + hh][r]);
                const float fv = __builtin_amdgcn_rcpf(1.0f + ef);
                const float ig = (1.0f - eg) * __builtin_amdgcn_rcpf((1.0f + ei) * (1.0f + eg));
                c[hh][r] = fmaf(fv, c[hh][r], ig);
                const float ec = exp2c(-2.88539008f * c[hh][r]);
                const float hv = (1.0f - ec) * __builtin_amdgcn_rcpf((1.0f + eo) * (1.0f + ec));
                hlds[khi * 4 + r][hh * 16 + n16] = (_Float16)hv;
            }
        }

        // next-step x-part MFMAs (independent of h) fill the write->read gap.
        ax[0] = (_Float16)xn0.x; ax[1] = (_Float16)xn0.y;
        ax[2] = (_Float16)xn1.x; ax[3] = (_Float16)xn1.y;
        ax[4] = (_Float16)xn2.x; ax[5] = (_Float16)xn2.y;
        #pragma unroll
        for (int q = 0; q < 8; ++q)
            dx[q] = __builtin_amdgcn_mfma_f32_16x16x32_f16(ax, bih[q], zf, 0, 0, 0);

        const int tn = (t + 2 < TSTEPS) ? (t + 2) : (TSTEPS - 1);
        const float2* pn = (const float2*)(xb + tn * ISZ);
        xn0 = pn[0]; xn1 = pn[1]; xn2 = pn[2];

        __builtin_amdgcn_wave_barrier();
    }

    // ---- MLP head: lane = (batch n16, unit-quarter khi) ----
    __builtin_amdgcn_wave_barrier();
    float hr[32];
    #pragma unroll
    for (int q8 = 0; q8 < 4; ++q8) {
        const h8_t hv = *(const h8_t*)&hlds[n16][q8 * 8];
        #pragma unroll
        for (int e = 0; e < 8; ++e) hr[q8 * 8 + e] = (float)hv[e];
    }
    float rsum = 0.0f;
    #pragma unroll
    for (int u = 0; u < 16; ++u) {
        const int row = khi * 16 + u;
        float a = b1s[row];
        #pragma unroll
        for (int k = 0; k < 32; k += 2) {
            const float2 w = *(const float2*)&w1s[row * 34 + k];
            a = fmaf(w.x, hr[k], a);
            a = fmaf(w.y, hr[k + 1], a);
        }
        rsum = fmaf(fmaxf(a, 0.0f), w2s[row], rsum);
    }
    rsum += __shfl_xor(rsum, 16, 64);
    rsum += __shfl_xor(rsum, 32, 64);
    if (khi == 0) out[blockIdx.x * NB + n16] = rsum + b2[0];
}

extern "C" void kernel_launch(void* const* d_in, const int* in_sizes, int n_in,
                              void* d_out, int out_size, void* d_ws, size_t ws_size,
                              hipStream_t stream) {
    const float* x    = (const float*)d_in[0];
    const float* W_ih = (const float*)d_in[1];
    const float* W_hh = (const float*)d_in[2];
    const float* b_ih = (const float*)d_in[3];
    const float* b_hh = (const float*)d_in[4];
    const float* W1   = (const float*)d_in[5];
    const float* b1   = (const float*)d_in[6];
    const float* W2   = (const float*)d_in[7];
    const float* b2   = (const float*)d_in[8];
    float* out = (float*)d_out;

    const int B = in_sizes[0] / (TSTEPS * ISZ);   // 8192
    const int grid = B / NB;                      // 512 one-wave blocks

    lstm_wave<<<grid, 64, 0, stream>>>(x, W_ih, W_hh, b_ih, b_hh,
                                       W1, b1, W2, b2, out);
}